// Round 1
// 1383.250 us; speedup vs baseline: 1.1621x; 1.1621x over previous
//
#include <hip/hip_runtime.h>
#include <math.h>

#define IMG 48
#define NPIX 2304
#define CH 128
#define NHEADS 8
#define HDIM 16
#define QK_SCALE 0.14433756729740643f   // 1/sqrt(48)
#define LN1E4 9.210340371976184f        // ln(10000)

// =====================================================================
// Kernel 1: complex conv for q,k,v  + bias + rotary + polar transform.
// Block: 256 threads, channel pair (co0, co0+1) x 6-row tile.
// Grid: (8 tiles, 64 pairs).
// Change vs prev: stage 4 input planes per barrier round (128 -> 32
// rounds; 12.5 staging loads in flight per thread instead of 3.1).
// =====================================================================
__global__ __launch_bounds__(256) void conv_qkv_kernel(
    const float* __restrict__ xr_g, const float* __restrict__ xi_g,
    const float* __restrict__ wq_r, const float* __restrict__ wq_i,
    const float* __restrict__ bq_r, const float* __restrict__ bq_i,
    const float* __restrict__ wk_r, const float* __restrict__ wk_i,
    const float* __restrict__ bk_r, const float* __restrict__ bk_i,
    const float* __restrict__ wv_r, const float* __restrict__ wv_i,
    const float* __restrict__ bv_r, const float* __restrict__ bv_i,
    float* __restrict__ qm_ws, float* __restrict__ qp_ws,
    float* __restrict__ km_ws, float* __restrict__ kp_ws,
    float* __restrict__ vmp_ws)
{
    __shared__ float wlds[CH * 9 * 12];     // [ci][tap][12], 55,296 B
    __shared__ float xlds[4][2][8][50];     // 4 planes x (re,im) padded rows, 12,800 B

    const int tid  = threadIdx.x;
    const int tile = blockIdx.x;            // 0..7 (6 rows each)
    const int pair = blockIdx.y;            // 0..63
    const int co0  = pair * 2;
    const int y0   = tile * 6;

    // ---- stage weights into LDS (one time) ----
    {
        const float* wptr[6] = { wq_r, wq_i, wk_r, wk_i, wv_r, wv_i };
        for (int k12 = 0; k12 < 12; ++k12) {
            const int c = k12 / 6, cv = k12 % 6;
            const float* src = wptr[cv] + (co0 + c) * (CH * 9);
            for (int i = tid; i < CH * 9; i += 256)
                wlds[i * 12 + k12] = src[i];
        }
    }

    float acc[2][12];
    #pragma unroll
    for (int j = 0; j < 2; ++j)
        #pragma unroll
        for (int q = 0; q < 12; ++q) acc[j][q] = 0.f;

    for (int cb = 0; cb < CH; cb += 4) {
        __syncthreads();
        // stage 4 padded x planes (re+im): 3200 floats
        for (int i = tid; i < 4 * 2 * 8 * 50; i += 256) {
            const int ci4  = i / 800;
            const int rem  = i % 800;
            const int comp = rem / 400;
            const int rem2 = rem % 400;
            const int row  = rem2 / 50;
            const int col  = rem2 % 50;
            const int gy = y0 - 1 + row;
            const int gx = col - 1;
            float v = 0.f;
            if ((unsigned)gy < IMG && (unsigned)gx < IMG)
                v = (comp ? xi_g : xr_g)[(cb + ci4) * NPIX + gy * IMG + gx];
            xlds[ci4][comp][row][col] = v;
        }
        __syncthreads();

        #pragma unroll
        for (int ci4 = 0; ci4 < 4; ++ci4) {
            const float* wrow = &wlds[(cb + ci4) * 108];
            for (int tap = 0; tap < 9; ++tap) {
                const int ky = tap / 3, kx = tap % 3;
                const float4 w0 = *(const float4*)&wrow[tap * 12 + 0];
                const float4 w1 = *(const float4*)&wrow[tap * 12 + 4];
                const float4 w2 = *(const float4*)&wrow[tap * 12 + 8];
                #pragma unroll
                for (int j = 0; j < 2; ++j) {
                    const int px = tid + j * 256;
                    if (px < 288) {
                        const int row = px / 48, col = px % 48;
                        const float xr = xlds[ci4][0][row + ky][col + kx];
                        const float xi = xlds[ci4][1][row + ky][col + kx];
                        float* a = acc[j];
                        a[0]  = fmaf(xr, w0.x, a[0]);  a[0]  = fmaf(-xi, w0.y, a[0]);
                        a[1]  = fmaf(xr, w0.y, a[1]);  a[1]  = fmaf( xi, w0.x, a[1]);
                        a[2]  = fmaf(xr, w0.z, a[2]);  a[2]  = fmaf(-xi, w0.w, a[2]);
                        a[3]  = fmaf(xr, w0.w, a[3]);  a[3]  = fmaf( xi, w0.z, a[3]);
                        a[4]  = fmaf(xr, w1.x, a[4]);  a[4]  = fmaf(-xi, w1.y, a[4]);
                        a[5]  = fmaf(xr, w1.y, a[5]);  a[5]  = fmaf( xi, w1.x, a[5]);
                        a[6]  = fmaf(xr, w1.z, a[6]);  a[6]  = fmaf(-xi, w1.w, a[6]);
                        a[7]  = fmaf(xr, w1.w, a[7]);  a[7]  = fmaf( xi, w1.z, a[7]);
                        a[8]  = fmaf(xr, w2.x, a[8]);  a[8]  = fmaf(-xi, w2.y, a[8]);
                        a[9]  = fmaf(xr, w2.y, a[9]);  a[9]  = fmaf( xi, w2.x, a[9]);
                        a[10] = fmaf(xr, w2.z, a[10]); a[10] = fmaf(-xi, w2.w, a[10]);
                        a[11] = fmaf(xr, w2.w, a[11]); a[11] = fmaf( xi, w2.z, a[11]);
                    }
                }
            }
        }
    }

    // ---- epilogue: bias, rotary (q,k), polar, store ----
    const int h  = co0 >> 4;
    const int d0 = co0 & 15;   // even
    const float bqr0 = bq_r[co0],     bqi0 = bq_i[co0];
    const float bkr0 = bk_r[co0],     bki0 = bk_i[co0];
    const float bvr0 = bv_r[co0],     bvi0 = bv_i[co0];
    const float bqr1 = bq_r[co0 + 1], bqi1 = bq_i[co0 + 1];
    const float bkr1 = bk_r[co0 + 1], bki1 = bk_i[co0 + 1];
    const float bvr1 = bv_r[co0 + 1], bvi1 = bv_i[co0 + 1];
    const float inv_freq = expf(-(float)d0 * (LN1E4 / 16.0f));

    #pragma unroll
    for (int j = 0; j < 2; ++j) {
        const int px = tid + j * 256;
        if (px < 288) {
            const int n = y0 * IMG + px;
            const float ang = (float)n * inv_freq;
            const float cs = cosf(ang), sn = sinf(ang);
            float* a = acc[j];
            float qre = a[0] + bqr0, qie = a[1] + bqi0;
            float kre = a[2] + bkr0, kie = a[3] + bki0;
            float vre = a[4] + bvr0, vie = a[5] + bvi0;
            float qro = a[6] + bqr1, qio = a[7] + bqi1;
            float kro = a[8] + bkr1, kio = a[9] + bki1;
            float vro = a[10] + bvr1, vio = a[11] + bvi1;
            float t;
            t = qre * cs - qro * sn; qro = qro * cs + qre * sn; qre = t;
            t = qie * cs - qio * sn; qio = qio * cs + qie * sn; qie = t;
            t = kre * cs - kro * sn; kro = kro * cs + kre * sn; kre = t;
            t = kie * cs - kio * sn; kio = kio * cs + kie * sn; kie = t;

            const int base = (h * NPIX + n) * HDIM + d0;
            float2 f2;
            f2.x = sqrtf(qre * qre + qie * qie);
            f2.y = sqrtf(qro * qro + qio * qio);
            *(float2*)&qm_ws[base] = f2;
            f2.x = atan2f(qie, qre);
            f2.y = atan2f(qio, qro);
            *(float2*)&qp_ws[base] = f2;
            f2.x = sqrtf(kre * kre + kie * kie);
            f2.y = sqrtf(kro * kro + kio * kio);
            *(float2*)&km_ws[base] = f2;
            f2.x = atan2f(kie, kre);
            f2.y = atan2f(kio, kro);
            *(float2*)&kp_ws[base] = f2;
            float4 v4;
            v4.x = sqrtf(vre * vre + vie * vie);
            v4.y = atan2f(vie, vre);
            v4.z = sqrtf(vro * vro + vio * vio);
            v4.w = atan2f(vio, vro);
            *(float4*)&vmp_ws[base * 2] = v4;
        }
    }
}

// =====================================================================
// Kernel 2: fused attention (f32 softmax end-to-end, f32 outputs).
// Block: 256 threads = 4 waves; EACH WAVE OWNS ONE QUERY ROW (64 lanes).
// Grid: 4608 blocks; h = bid & 7 (XCD L2 locality), row tile = (bid>>3)*4.
// LDS 36,864 B -> 4 blocks/CU (was 74,240 B -> 2 blocks/CU).
// No __syncthreads at all: each wave's plds row is wave-private.
// =====================================================================
__global__ __launch_bounds__(256, 4) void attn_kernel(
    const float* __restrict__ qm_ws, const float* __restrict__ qp_ws,
    const float* __restrict__ km_ws, const float* __restrict__ kp_ws,
    const float* __restrict__ vmp_ws,
    float* __restrict__ qkm_out, float* __restrict__ qkp_out,
    float* __restrict__ ar_ws, float* __restrict__ ai_ws)
{
    __shared__ float plds[4][NPIX];       // f32 scores/probs, 36,864 B

    const int tid = threadIdx.x;
    const int bid = blockIdx.x;           // 0..4607
    const int h   = bid & 7;
    const int r0  = (bid >> 3) * 4;
    const int r   = tid >> 6;             // wave id = row index
    const int ml  = tid & 63;             // lane within wave
    const int n   = r0 + r;               // query row

    // q row fragments in registers (broadcast: 64 lanes share r)
    float qmr[16], qpr[16];
    {
        const float* qmp = qm_ws + ((size_t)h * NPIX + n) * HDIM;
        const float* qpp = qp_ws + ((size_t)h * NPIX + n) * HDIM;
        #pragma unroll
        for (int d = 0; d < 16; d += 4) {
            const float4 a = *(const float4*)&qmp[d];
            const float4 b = *(const float4*)&qpp[d];
            qmr[d] = a.x; qmr[d + 1] = a.y; qmr[d + 2] = a.z; qmr[d + 3] = a.w;
            qpr[d] = b.x; qpr[d + 1] = b.y; qpr[d + 2] = b.z; qpr[d + 3] = b.w;
        }
    }

    // ---- pass 1: scores (identical fp32 dot order => qkm/qkp bits unchanged)
    float lmax = 0.f;   // |s| >= 0
    #pragma unroll 2
    for (int g = 0; g < 36; ++g) {
        const int m = ml + (g << 6);
        const float* kmp = km_ws + ((size_t)h * NPIX + m) * HDIM;
        const float* kpp = kp_ws + ((size_t)h * NPIX + m) * HDIM;
        float sm = 0.f, sp = 0.f;
        #pragma unroll
        for (int d = 0; d < 16; d += 4) {
            const float4 a = *(const float4*)&kmp[d];
            const float4 b = *(const float4*)&kpp[d];
            sm = fmaf(qmr[d], a.x, sm);     sm = fmaf(qmr[d + 1], a.y, sm);
            sm = fmaf(qmr[d + 2], a.z, sm); sm = fmaf(qmr[d + 3], a.w, sm);
            sp = fmaf(qpr[d], b.x, sp);     sp = fmaf(qpr[d + 1], b.y, sp);
            sp = fmaf(qpr[d + 2], b.z, sp); sp = fmaf(qpr[d + 3], b.w, sp);
        }
        sm *= QK_SCALE; sp *= QK_SCALE;
        const size_t ob = ((size_t)h * NPIX + n) * NPIX + m;
        // streaming 340 MB output: don't evict L2-resident K/V
        __builtin_nontemporal_store(sm, &qkm_out[ob]);
        __builtin_nontemporal_store(sp, &qkp_out[ob]);
        const float as = fabsf(sm);
        plds[r][m] = as;
        lmax = fmaxf(lmax, as);
    }
    #pragma unroll
    for (int mask = 1; mask < 64; mask <<= 1)
        lmax = fmaxf(lmax, __shfl_xor(lmax, mask));

    // ---- pass 2: exp + row sum (wave-private row, no barrier needed) ----
    float lsum = 0.f;
    for (int g = 0; g < 36; ++g) {
        const int m = ml + (g << 6);
        const float p = expf(plds[r][m] - lmax);
        lsum += p;
        plds[r][m] = p;
    }
    #pragma unroll
    for (int mask = 1; mask < 64; mask <<= 1)
        lsum += __shfl_xor(lsum, mask);
    __builtin_amdgcn_wave_barrier();   // scheduling fence only, zero cost

    // ---- pass 3: P.V, lane = (oct, dpair): oct covers m mod 16, dpair covers 2 d's
    const int dp  = ml & 7;           // d = 2*dp, 2*dp+1
    const int oct = ml >> 3;          // 0..7
    float am0 = 0.f, ap0 = 0.f, am1 = 0.f, ap1 = 0.f;
    const float* vb = vmp_ws + (size_t)h * NPIX * 32 + dp * 4;
    #pragma unroll 4
    for (int g = 0; g < 144; ++g) {
        const int m0 = (g << 4) + (oct << 1);
        const float2 p2 = *(const float2*)&plds[r][m0];
        const float4 va = *(const float4*)&vb[(size_t)m0 * 32];
        const float4 vc = *(const float4*)&vb[(size_t)(m0 + 1) * 32];
        am0 = fmaf(p2.x, va.x, am0); ap0 = fmaf(p2.x, va.y, ap0);
        am1 = fmaf(p2.x, va.z, am1); ap1 = fmaf(p2.x, va.w, ap1);
        am0 = fmaf(p2.y, vc.x, am0); ap0 = fmaf(p2.y, vc.y, ap0);
        am1 = fmaf(p2.y, vc.z, am1); ap1 = fmaf(p2.y, vc.w, ap1);
    }
    #pragma unroll
    for (int mask = 8; mask < 64; mask <<= 1) {
        am0 += __shfl_xor(am0, mask);
        ap0 += __shfl_xor(ap0, mask);
        am1 += __shfl_xor(am1, mask);
        ap1 += __shfl_xor(ap1, mask);
    }
    if (oct == 0) {
        const float om0 = am0 / lsum, op0 = ap0 / lsum;
        const float om1 = am1 / lsum, op1 = ap1 / lsum;
        const int c = h * HDIM + dp * 2;
        ar_ws[c * NPIX + n]       = om0 * cosf(op0);
        ai_ws[c * NPIX + n]       = om0 * sinf(op0);
        ar_ws[(c + 1) * NPIX + n] = om1 * cosf(op1);
        ai_ws[(c + 1) * NPIX + n] = om1 * sinf(op1);
    }
}

// =====================================================================
// Kernel 3: output complex conv from a_r/a_i (NCHW f32 in ws) -> o_r,o_i f32
// Same 4-planes-per-round staging as kernel 1.
// =====================================================================
__global__ __launch_bounds__(256) void conv_o_kernel(
    const float* __restrict__ ar_g, const float* __restrict__ ai_g,
    const float* __restrict__ wo_r, const float* __restrict__ wo_i,
    const float* __restrict__ bo_r, const float* __restrict__ bo_i,
    float* __restrict__ or_out, float* __restrict__ oi_out)
{
    __shared__ float wlds[CH * 9 * 4];    // [ci][tap][4]: wr0, wi0, wr1, wi1
    __shared__ float xlds[4][2][8][50];

    const int tid  = threadIdx.x;
    const int tile = blockIdx.x;          // 0..7
    const int pair = blockIdx.y;          // 0..63
    const int co0  = pair * 2;
    const int y0   = tile * 6;

    {
        for (int k4 = 0; k4 < 4; ++k4) {
            const int c = k4 >> 1;
            const float* src = ((k4 & 1) ? wo_i : wo_r) + (co0 + c) * (CH * 9);
            for (int i = tid; i < CH * 9; i += 256)
                wlds[i * 4 + k4] = src[i];
        }
    }

    float acc[2][4];
    #pragma unroll
    for (int j = 0; j < 2; ++j)
        #pragma unroll
        for (int q = 0; q < 4; ++q) acc[j][q] = 0.f;

    for (int cb = 0; cb < CH; cb += 4) {
        __syncthreads();
        for (int i = tid; i < 4 * 2 * 8 * 50; i += 256) {
            const int ci4  = i / 800;
            const int rem  = i % 800;
            const int comp = rem / 400;
            const int rem2 = rem % 400;
            const int row  = rem2 / 50;
            const int col  = rem2 % 50;
            const int gy = y0 - 1 + row;
            const int gx = col - 1;
            float v = 0.f;
            if ((unsigned)gy < IMG && (unsigned)gx < IMG)
                v = (comp ? ai_g : ar_g)[(cb + ci4) * NPIX + gy * IMG + gx];
            xlds[ci4][comp][row][col] = v;
        }
        __syncthreads();

        #pragma unroll
        for (int ci4 = 0; ci4 < 4; ++ci4) {
            const float* wrow = &wlds[(cb + ci4) * 36];
            for (int tap = 0; tap < 9; ++tap) {
                const int ky = tap / 3, kx = tap % 3;
                const float4 w = *(const float4*)&wrow[tap * 4];
                #pragma unroll
                for (int j = 0; j < 2; ++j) {
                    const int px = tid + j * 256;
                    if (px < 288) {
                        const int row = px / 48, col = px % 48;
                        const float ar = xlds[ci4][0][row + ky][col + kx];
                        const float ai = xlds[ci4][1][row + ky][col + kx];
                        float* a = acc[j];
                        a[0] = fmaf(ar, w.x, a[0]); a[0] = fmaf(-ai, w.y, a[0]);
                        a[1] = fmaf(ar, w.y, a[1]); a[1] = fmaf( ai, w.x, a[1]);
                        a[2] = fmaf(ar, w.z, a[2]); a[2] = fmaf(-ai, w.w, a[2]);
                        a[3] = fmaf(ar, w.w, a[3]); a[3] = fmaf( ai, w.z, a[3]);
                    }
                }
            }
        }
    }

    const float br0 = bo_r[co0],     bi0 = bo_i[co0];
    const float br1 = bo_r[co0 + 1], bi1 = bo_i[co0 + 1];
    #pragma unroll
    for (int j = 0; j < 2; ++j) {
        const int px = tid + j * 256;
        if (px < 288) {
            const int n = y0 * IMG + px;
            or_out[co0 * NPIX + n]       = acc[j][0] + br0;
            oi_out[co0 * NPIX + n]       = acc[j][1] + bi0;
            or_out[(co0 + 1) * NPIX + n] = acc[j][2] + br1;
            oi_out[(co0 + 1) * NPIX + n] = acc[j][3] + bi1;
        }
    }
}

// =====================================================================
extern "C" void kernel_launch(void* const* d_in, const int* in_sizes, int n_in,
                              void* d_out, int out_size, void* d_ws, size_t ws_size,
                              hipStream_t stream)
{
    const float* xr   = (const float*)d_in[0];
    const float* xi   = (const float*)d_in[1];
    const float* wq_r = (const float*)d_in[2];
    const float* wq_i = (const float*)d_in[3];
    const float* bq_r = (const float*)d_in[4];
    const float* bq_i = (const float*)d_in[5];
    const float* wk_r = (const float*)d_in[6];
    const float* wk_i = (const float*)d_in[7];
    const float* bk_r = (const float*)d_in[8];
    const float* bk_i = (const float*)d_in[9];
    const float* wv_r = (const float*)d_in[10];
    const float* wv_i = (const float*)d_in[11];
    const float* bv_r = (const float*)d_in[12];
    const float* bv_i = (const float*)d_in[13];
    const float* wo_r = (const float*)d_in[14];
    const float* wo_i = (const float*)d_in[15];
    const float* bo_r = (const float*)d_in[16];
    const float* bo_i = (const float*)d_in[17];

    float* ws  = (float*)d_ws;
    float* qm  = ws;
    float* qp  = qm  + 294912;
    float* km  = qp  + 294912;
    float* kp  = km  + 294912;
    float* vmp = kp  + 294912;        // 589824 floats (interleaved vm,vp)
    float* ar  = vmp + 589824;
    float* ai  = ar  + 294912;

    float* out = (float*)d_out;       // f32: reference output dtype
    float* o_r = out;
    float* o_i = out + 294912;
    float* qkm = out + 589824;
    float* qkp = qkm + 42467328;

    conv_qkv_kernel<<<dim3(8, 64), 256, 0, stream>>>(
        xr, xi, wq_r, wq_i, bq_r, bq_i, wk_r, wk_i, bk_r, bk_i,
        wv_r, wv_i, bv_r, bv_i, qm, qp, km, kp, vmp);

    attn_kernel<<<dim3(4608), 256, 0, stream>>>(
        qm, qp, km, kp, vmp, qkm, qkp, ar, ai);

    conv_o_kernel<<<dim3(8, 64), 256, 0, stream>>>(
        ar, ai, wo_r, wo_i, bo_r, bo_i, o_r, o_i);
}

// Round 2
// 813.830 us; speedup vs baseline: 1.9751x; 1.6997x over previous
//
#include <hip/hip_runtime.h>
#include <math.h>

#define IMG 48
#define NPIX 2304
#define CH 128
#define NHEADS 8
#define HDIM 16
#define QK_SCALE 0.14433756729740643f   // 1/sqrt(48)
#define LN1E4 9.210340371976184f        // ln(10000)

// =====================================================================
// Kernel 1: complex conv q,k,v + bias + rotary + polar.
// Block: 256 threads = EXACTLY 256 px (tile*256..+255), channel pair.
// Grid: (9 tiles, 64 pairs) = 576 blocks. No masked j-pass, no straggler.
// Weights staged per-round (216 floats) -> LDS 14.5 KB total.
// T14 pipeline: one barrier/round, loads issue before compute.
// =====================================================================
__global__ __launch_bounds__(256) void conv_qkv_kernel(
    const float* __restrict__ xr_g, const float* __restrict__ xi_g,
    const float* __restrict__ wq_r, const float* __restrict__ wq_i,
    const float* __restrict__ bq_r, const float* __restrict__ bq_i,
    const float* __restrict__ wk_r, const float* __restrict__ wk_i,
    const float* __restrict__ bk_r, const float* __restrict__ bk_i,
    const float* __restrict__ wv_r, const float* __restrict__ wv_i,
    const float* __restrict__ bv_r, const float* __restrict__ bv_i,
    float* __restrict__ qm_ws, float* __restrict__ qp_ws,
    float* __restrict__ km_ws, float* __restrict__ kp_ws,
    float* __restrict__ vmp_ws)
{
    __shared__ __align__(16) float xlds[2][2][2][8][50];  // [buf][pl][comp][row][col] 12,800 B
    __shared__ __align__(16) float wlds[2][216];          // [buf][pl*108+tap*12+s]     1,728 B

    const int tid  = threadIdx.x;
    const int tile = blockIdx.x;          // 0..8
    const int pair = blockIdx.y;          // 0..63
    const int co0  = pair * 2;
    const int px   = tile * 256 + tid;    // 0..2303
    const int row0 = (tile * 256) / 48;
    const int myrow = px / 48 - row0;     // 0..5
    const int mycol = px % 48;

    // ---- staging slot precompute (7 x-slots + 1 w-slot per thread) ----
    const float* gptr[7];
    int gofs[7], lofs[7];
    #pragma unroll
    for (int j = 0; j < 7; ++j) {
        const int i = tid + j * 256;
        if (i < 1600) {
            const int pl   = i / 800;
            const int rem  = i % 800;
            const int comp = rem / 400;
            const int rem2 = rem % 400;
            const int row  = rem2 / 50;
            const int col  = rem2 % 50;
            const int gy = row0 - 1 + row;
            const int gx = col - 1;
            const bool ok = ((unsigned)gy < IMG) && ((unsigned)gx < IMG);
            gptr[j] = comp ? xi_g : xr_g;
            gofs[j] = ok ? (pl * NPIX + gy * IMG + gx) : -1;
            lofs[j] = ((pl * 2 + comp) * 8 + row) * 50 + col;
        } else { gptr[j] = xr_g; gofs[j] = -1; lofs[j] = -1; }
    }
    const float* wsrc = xr_g;
    if (tid < 216) {
        const int pl = tid / 108, r108 = tid % 108;
        const int tap = r108 / 12, s = r108 % 12;
        const int c = s / 6, v = s % 6;
        const float* wp =
            (v == 0) ? wq_r : (v == 1) ? wq_i :
            (v == 2) ? wk_r : (v == 3) ? wk_i :
            (v == 4) ? wv_r : wv_i;
        wsrc = wp + (co0 + c) * (CH * 9) + pl * 9 + tap;
    }

    float* xfl = &xlds[0][0][0][0][0];
    float xv[7]; float wv;

    auto LOADR = [&](int t) {
        #pragma unroll
        for (int j = 0; j < 7; ++j)
            xv[j] = (gofs[j] >= 0) ? gptr[j][t * 2 * NPIX + gofs[j]] : 0.f;
        if (tid < 216) wv = wsrc[t * 18];
    };
    auto WRITE = [&](int b) {
        #pragma unroll
        for (int j = 0; j < 7; ++j)
            if (lofs[j] >= 0) xfl[b * 1600 + lofs[j]] = xv[j];
        if (tid < 216) wlds[b][tid] = wv;
    };

    float acc[12];
    #pragma unroll
    for (int q = 0; q < 12; ++q) acc[q] = 0.f;

    auto COMPUTE = [&](int p) {
        #pragma unroll
        for (int pl = 0; pl < 2; ++pl) {
            const float* wrow = &wlds[p][pl * 108];
            #pragma unroll
            for (int tap = 0; tap < 9; ++tap) {
                const int ky = tap / 3, kx = tap % 3;
                const float4 w0 = *(const float4*)&wrow[tap * 12 + 0];
                const float4 w1 = *(const float4*)&wrow[tap * 12 + 4];
                const float4 w2 = *(const float4*)&wrow[tap * 12 + 8];
                const float xr = xlds[p][pl][0][myrow + ky][mycol + kx];
                const float xi = xlds[p][pl][1][myrow + ky][mycol + kx];
                acc[0]  = fmaf(xr, w0.x, acc[0]);  acc[0]  = fmaf(-xi, w0.y, acc[0]);
                acc[1]  = fmaf(xr, w0.y, acc[1]);  acc[1]  = fmaf( xi, w0.x, acc[1]);
                acc[2]  = fmaf(xr, w0.z, acc[2]);  acc[2]  = fmaf(-xi, w0.w, acc[2]);
                acc[3]  = fmaf(xr, w0.w, acc[3]);  acc[3]  = fmaf( xi, w0.z, acc[3]);
                acc[4]  = fmaf(xr, w1.x, acc[4]);  acc[4]  = fmaf(-xi, w1.y, acc[4]);
                acc[5]  = fmaf(xr, w1.y, acc[5]);  acc[5]  = fmaf( xi, w1.x, acc[5]);
                acc[6]  = fmaf(xr, w1.z, acc[6]);  acc[6]  = fmaf(-xi, w1.w, acc[6]);
                acc[7]  = fmaf(xr, w1.w, acc[7]);  acc[7]  = fmaf( xi, w1.z, acc[7]);
                acc[8]  = fmaf(xr, w2.x, acc[8]);  acc[8]  = fmaf(-xi, w2.y, acc[8]);
                acc[9]  = fmaf(xr, w2.y, acc[9]);  acc[9]  = fmaf( xi, w2.x, acc[9]);
                acc[10] = fmaf(xr, w2.z, acc[10]); acc[10] = fmaf(-xi, w2.w, acc[10]);
                acc[11] = fmaf(xr, w2.w, acc[11]); acc[11] = fmaf( xi, w2.z, acc[11]);
            }
        }
    };

    LOADR(0); WRITE(0); LOADR(1);
    __syncthreads();
    for (int rr = 0; rr < 64; ++rr) {
        const int p = rr & 1;
        if (rr + 1 < 64) WRITE(p ^ 1);     // regs hold tile rr+1
        if (rr + 2 < 64) LOADR(rr + 2);    // issue; latency hides under compute
        COMPUTE(p);
        __syncthreads();
    }

    // ---- epilogue: bias, rotary, polar, store (one px per thread) ----
    const int h  = co0 >> 4;
    const int d0 = co0 & 15;   // even
    const float bqr0 = bq_r[co0],     bqi0 = bq_i[co0];
    const float bkr0 = bk_r[co0],     bki0 = bk_i[co0];
    const float bvr0 = bv_r[co0],     bvi0 = bv_i[co0];
    const float bqr1 = bq_r[co0 + 1], bqi1 = bq_i[co0 + 1];
    const float bkr1 = bk_r[co0 + 1], bki1 = bk_i[co0 + 1];
    const float bvr1 = bv_r[co0 + 1], bvi1 = bv_i[co0 + 1];
    const float inv_freq = expf(-(float)d0 * (LN1E4 / 16.0f));

    const int n = px;
    const float ang = (float)n * inv_freq;
    const float cs = cosf(ang), sn = sinf(ang);
    float qre = acc[0] + bqr0, qie = acc[1] + bqi0;
    float kre = acc[2] + bkr0, kie = acc[3] + bki0;
    float vre = acc[4] + bvr0, vie = acc[5] + bvi0;
    float qro = acc[6] + bqr1, qio = acc[7] + bqi1;
    float kro = acc[8] + bkr1, kio = acc[9] + bki1;
    float vro = acc[10] + bvr1, vio = acc[11] + bvi1;
    float t;
    t = qre * cs - qro * sn; qro = qro * cs + qre * sn; qre = t;
    t = qie * cs - qio * sn; qio = qio * cs + qie * sn; qie = t;
    t = kre * cs - kro * sn; kro = kro * cs + kre * sn; kre = t;
    t = kie * cs - kio * sn; kio = kio * cs + kie * sn; kie = t;

    const int base = (h * NPIX + n) * HDIM + d0;
    float2 f2;
    f2.x = sqrtf(qre * qre + qie * qie);
    f2.y = sqrtf(qro * qro + qio * qio);
    *(float2*)&qm_ws[base] = f2;
    f2.x = atan2f(qie, qre);
    f2.y = atan2f(qio, qro);
    *(float2*)&qp_ws[base] = f2;
    f2.x = sqrtf(kre * kre + kie * kie);
    f2.y = sqrtf(kro * kro + kio * kio);
    *(float2*)&km_ws[base] = f2;
    f2.x = atan2f(kie, kre);
    f2.y = atan2f(kio, kro);
    *(float2*)&kp_ws[base] = f2;
    float4 v4;
    v4.x = sqrtf(vre * vre + vie * vie);
    v4.y = atan2f(vie, vre);
    v4.z = sqrtf(vro * vro + vio * vio);
    v4.w = atan2f(vio, vro);
    *(float4*)&vmp_ws[base * 2] = v4;
}

// =====================================================================
// Kernel 2: fused attention. 4 waves = 4 query rows per block.
// NEW: K/V staged in double-buffered 64-row LDS tiles shared by the 4
// waves (L2 read traffic /4), XOR-swizzled (col c stored at c^((row>>1)&7))
// to kill the 128 B-stride bank conflict. One barrier per tile (T14).
// LDS: plds 36,864 + kvlds 16,384 = 53,248 B -> 3 blocks/CU.
// =====================================================================
__global__ __launch_bounds__(256, 3) void attn_kernel(
    const float* __restrict__ qm_ws, const float* __restrict__ qp_ws,
    const float* __restrict__ km_ws, const float* __restrict__ kp_ws,
    const float* __restrict__ vmp_ws,
    float* __restrict__ qkm_out, float* __restrict__ qkp_out,
    float* __restrict__ ar_ws, float* __restrict__ ai_ws)
{
    __shared__ __align__(16) float plds[4][NPIX];     // probs, 36,864 B
    __shared__ __align__(16) float kvlds[2][64][32];  // K or V tile, swizzled, 16,384 B

    const int tid = threadIdx.x;
    const int bid = blockIdx.x;           // 0..4607
    const int h   = bid & 7;              // head -> XCD (L2 locality)
    const int r0  = (bid >> 3) * 4;
    const int r   = tid >> 6;             // wave id = row index
    const int ml  = tid & 63;
    const int n   = r0 + r;

    // q row fragments (broadcast within wave)
    float qmr[16], qpr[16];
    {
        const float* qmp = qm_ws + ((size_t)h * NPIX + n) * HDIM;
        const float* qpp = qp_ws + ((size_t)h * NPIX + n) * HDIM;
        #pragma unroll
        for (int d = 0; d < 16; d += 4) {
            const float4 a = *(const float4*)&qmp[d];
            const float4 b = *(const float4*)&qpp[d];
            qmr[d] = a.x; qmr[d + 1] = a.y; qmr[d + 2] = a.z; qmr[d + 3] = a.w;
            qpr[d] = b.x; qpr[d + 1] = b.y; qpr[d + 2] = b.z; qpr[d + 3] = b.w;
        }
    }

    // staging map: thread -> (row = tid>>2, word pair sc0 = (tid&3)*2)
    const int srow = tid >> 2;
    const int sc0  = (tid & 3) * 2;
    const int swr  = (srow >> 1) & 7;     // write-side swizzle
    const float* kmb = km_ws + (size_t)h * NPIX * HDIM;
    const float* kpb = kp_ws + (size_t)h * NPIX * HDIM;
    const float* vbb = vmp_ws + (size_t)h * NPIX * 32;
    const float* ks = (sc0 < 4)
        ? kmb + srow * HDIM + sc0 * 4
        : kpb + srow * HDIM + (sc0 - 4) * 4;
    const float* vsrc = vbb + srow * 32 + sc0 * 4;
    float* kw0 = &kvlds[0][srow][(sc0 ^ swr) * 4];
    float* kw1 = &kvlds[0][srow][((sc0 + 1) ^ swr) * 4];

    const int swl = (ml >> 1) & 7;        // read-side swizzle (pass 1, row=ml)

    // ================= pass 1: scores =================
    float4 na = *(const float4*)&ks[0];
    float4 nb = *(const float4*)&ks[4];
    *(float4*)kw0 = na;
    *(float4*)kw1 = nb;
    na = *(const float4*)&ks[1024];
    nb = *(const float4*)&ks[1028];
    __syncthreads();

    float lmax = 0.f;
    for (int g = 0; g < 36; ++g) {
        const int p = g & 1;
        if (g + 1 < 36) {                  // write tile g+1 into buf p^1
            *(float4*)(kw0 + (p ^ 1) * 2048) = na;
            *(float4*)(kw1 + (p ^ 1) * 2048) = nb;
        }
        if (g + 2 < 36) {                  // issue loads for tile g+2
            na = *(const float4*)&ks[(g + 2) * 1024];
            nb = *(const float4*)&ks[(g + 2) * 1024 + 4];
        }
        // compute: lane ml handles m = g*64 + ml, K row from LDS
        const float* krow = &kvlds[p][ml][0];
        float sm = 0.f, sp = 0.f;
        float4 a;
        a = *(const float4*)&krow[(0 ^ swl) * 4];
        sm = fmaf(qmr[0], a.x, sm);  sm = fmaf(qmr[1], a.y, sm);
        sm = fmaf(qmr[2], a.z, sm);  sm = fmaf(qmr[3], a.w, sm);
        a = *(const float4*)&krow[(1 ^ swl) * 4];
        sm = fmaf(qmr[4], a.x, sm);  sm = fmaf(qmr[5], a.y, sm);
        sm = fmaf(qmr[6], a.z, sm);  sm = fmaf(qmr[7], a.w, sm);
        a = *(const float4*)&krow[(2 ^ swl) * 4];
        sm = fmaf(qmr[8], a.x, sm);  sm = fmaf(qmr[9], a.y, sm);
        sm = fmaf(qmr[10], a.z, sm); sm = fmaf(qmr[11], a.w, sm);
        a = *(const float4*)&krow[(3 ^ swl) * 4];
        sm = fmaf(qmr[12], a.x, sm); sm = fmaf(qmr[13], a.y, sm);
        sm = fmaf(qmr[14], a.z, sm); sm = fmaf(qmr[15], a.w, sm);
        a = *(const float4*)&krow[(4 ^ swl) * 4];
        sp = fmaf(qpr[0], a.x, sp);  sp = fmaf(qpr[1], a.y, sp);
        sp = fmaf(qpr[2], a.z, sp);  sp = fmaf(qpr[3], a.w, sp);
        a = *(const float4*)&krow[(5 ^ swl) * 4];
        sp = fmaf(qpr[4], a.x, sp);  sp = fmaf(qpr[5], a.y, sp);
        sp = fmaf(qpr[6], a.z, sp);  sp = fmaf(qpr[7], a.w, sp);
        a = *(const float4*)&krow[(6 ^ swl) * 4];
        sp = fmaf(qpr[8], a.x, sp);  sp = fmaf(qpr[9], a.y, sp);
        sp = fmaf(qpr[10], a.z, sp); sp = fmaf(qpr[11], a.w, sp);
        a = *(const float4*)&krow[(7 ^ swl) * 4];
        sp = fmaf(qpr[12], a.x, sp); sp = fmaf(qpr[13], a.y, sp);
        sp = fmaf(qpr[14], a.z, sp); sp = fmaf(qpr[15], a.w, sp);

        sm *= QK_SCALE; sp *= QK_SCALE;
        const int m = (g << 6) + ml;
        const size_t ob = ((size_t)h * NPIX + n) * NPIX + m;
        __builtin_nontemporal_store(sm, &qkm_out[ob]);
        __builtin_nontemporal_store(sp, &qkp_out[ob]);
        const float as = fabsf(sm);
        plds[r][m] = as;
        lmax = fmaxf(lmax, as);
        __syncthreads();
    }
    #pragma unroll
    for (int mask = 1; mask < 64; mask <<= 1)
        lmax = fmaxf(lmax, __shfl_xor(lmax, mask));

    // ================= pass 2: exp + row sum (wave-private) =================
    float lsum = 0.f;
    for (int g = 0; g < 36; ++g) {
        const int m = ml + (g << 6);
        const float p = expf(plds[r][m] - lmax);
        lsum += p;
        plds[r][m] = p;
    }
    #pragma unroll
    for (int mask = 1; mask < 64; mask <<= 1)
        lsum += __shfl_xor(lsum, mask);
    __builtin_amdgcn_wave_barrier();

    // ================= pass 3: P.V with V tiles in LDS =================
    na = *(const float4*)&vsrc[0];
    nb = *(const float4*)&vsrc[4];
    *(float4*)kw0 = na;              // safe: all waves past pass-1 final barrier
    *(float4*)kw1 = nb;
    na = *(const float4*)&vsrc[2048];
    nb = *(const float4*)&vsrc[2052];
    __syncthreads();

    const int dp  = ml & 7;           // d pair: d = 2dp, 2dp+1
    const int oct = ml >> 3;          // 0..7: m mod 16 coverage
    const int vcol = (dp ^ oct) * 4;  // read-side swizzle (row>>1 & 7 == oct)
    float am0 = 0.f, ap0 = 0.f, am1 = 0.f, ap1 = 0.f;
    for (int g = 0; g < 36; ++g) {
        const int p = g & 1;
        if (g + 1 < 36) {
            *(float4*)(kw0 + (p ^ 1) * 2048) = na;
            *(float4*)(kw1 + (p ^ 1) * 2048) = nb;
        }
        if (g + 2 < 36) {
            na = *(const float4*)&vsrc[(g + 2) * 2048];
            nb = *(const float4*)&vsrc[(g + 2) * 2048 + 4];
        }
        #pragma unroll
        for (int s = 0; s < 4; ++s) {
            const int mr = s * 16 + oct * 2;
            const float2 p2 = *(const float2*)&plds[r][(g << 6) + mr];
            const float4 va = *(const float4*)&kvlds[p][mr][vcol];
            const float4 vc = *(const float4*)&kvlds[p][mr + 1][vcol];
            am0 = fmaf(p2.x, va.x, am0); ap0 = fmaf(p2.x, va.y, ap0);
            am1 = fmaf(p2.x, va.z, am1); ap1 = fmaf(p2.x, va.w, ap1);
            am0 = fmaf(p2.y, vc.x, am0); ap0 = fmaf(p2.y, vc.y, ap0);
            am1 = fmaf(p2.y, vc.z, am1); ap1 = fmaf(p2.y, vc.w, ap1);
        }
        __syncthreads();
    }
    #pragma unroll
    for (int mask = 8; mask < 64; mask <<= 1) {
        am0 += __shfl_xor(am0, mask);
        ap0 += __shfl_xor(ap0, mask);
        am1 += __shfl_xor(am1, mask);
        ap1 += __shfl_xor(ap1, mask);
    }
    if (oct == 0) {
        const float om0 = am0 / lsum, op0 = ap0 / lsum;
        const float om1 = am1 / lsum, op1 = ap1 / lsum;
        const int c = h * HDIM + dp * 2;
        ar_ws[c * NPIX + n]       = om0 * cosf(op0);
        ai_ws[c * NPIX + n]       = om0 * sinf(op0);
        ar_ws[(c + 1) * NPIX + n] = om1 * cosf(op1);
        ai_ws[(c + 1) * NPIX + n] = om1 * sinf(op1);
    }
}

// =====================================================================
// Kernel 3: output complex conv -- same 256-px / T14 structure as K1.
// =====================================================================
__global__ __launch_bounds__(256) void conv_o_kernel(
    const float* __restrict__ ar_g, const float* __restrict__ ai_g,
    const float* __restrict__ wo_r, const float* __restrict__ wo_i,
    const float* __restrict__ bo_r, const float* __restrict__ bo_i,
    float* __restrict__ or_out, float* __restrict__ oi_out)
{
    __shared__ __align__(16) float xlds[2][2][2][8][50];
    __shared__ __align__(16) float wlds[2][72];           // [buf][pl*36+tap*4+s]

    const int tid  = threadIdx.x;
    const int tile = blockIdx.x;          // 0..8
    const int pair = blockIdx.y;          // 0..63
    const int co0  = pair * 2;
    const int px   = tile * 256 + tid;
    const int row0 = (tile * 256) / 48;
    const int myrow = px / 48 - row0;
    const int mycol = px % 48;

    const float* gptr[7];
    int gofs[7], lofs[7];
    #pragma unroll
    for (int j = 0; j < 7; ++j) {
        const int i = tid + j * 256;
        if (i < 1600) {
            const int pl   = i / 800;
            const int rem  = i % 800;
            const int comp = rem / 400;
            const int rem2 = rem % 400;
            const int row  = rem2 / 50;
            const int col  = rem2 % 50;
            const int gy = row0 - 1 + row;
            const int gx = col - 1;
            const bool ok = ((unsigned)gy < IMG) && ((unsigned)gx < IMG);
            gptr[j] = comp ? ai_g : ar_g;
            gofs[j] = ok ? (pl * NPIX + gy * IMG + gx) : -1;
            lofs[j] = ((pl * 2 + comp) * 8 + row) * 50 + col;
        } else { gptr[j] = ar_g; gofs[j] = -1; lofs[j] = -1; }
    }
    const float* wsrc = ar_g;
    if (tid < 72) {
        const int pl = tid / 36, r36 = tid % 36;
        const int tap = r36 / 4, s = r36 % 4;
        const int c = s >> 1;
        const float* wp = (s & 1) ? wo_i : wo_r;
        wsrc = wp + (co0 + c) * (CH * 9) + pl * 9 + tap;
    }

    float* xfl = &xlds[0][0][0][0][0];
    float xv[7]; float wv;

    auto LOADR = [&](int t) {
        #pragma unroll
        for (int j = 0; j < 7; ++j)
            xv[j] = (gofs[j] >= 0) ? gptr[j][t * 2 * NPIX + gofs[j]] : 0.f;
        if (tid < 72) wv = wsrc[t * 18];
    };
    auto WRITE = [&](int b) {
        #pragma unroll
        for (int j = 0; j < 7; ++j)
            if (lofs[j] >= 0) xfl[b * 1600 + lofs[j]] = xv[j];
        if (tid < 72) wlds[b][tid] = wv;
    };

    float acc[4];
    #pragma unroll
    for (int q = 0; q < 4; ++q) acc[q] = 0.f;

    auto COMPUTE = [&](int p) {
        #pragma unroll
        for (int pl = 0; pl < 2; ++pl) {
            const float* wrow = &wlds[p][pl * 36];
            #pragma unroll
            for (int tap = 0; tap < 9; ++tap) {
                const int ky = tap / 3, kx = tap % 3;
                const float4 w = *(const float4*)&wrow[tap * 4];
                const float ar = xlds[p][pl][0][myrow + ky][mycol + kx];
                const float ai = xlds[p][pl][1][myrow + ky][mycol + kx];
                acc[0] = fmaf(ar, w.x, acc[0]); acc[0] = fmaf(-ai, w.y, acc[0]);
                acc[1] = fmaf(ar, w.y, acc[1]); acc[1] = fmaf( ai, w.x, acc[1]);
                acc[2] = fmaf(ar, w.z, acc[2]); acc[2] = fmaf(-ai, w.w, acc[2]);
                acc[3] = fmaf(ar, w.w, acc[3]); acc[3] = fmaf( ai, w.z, acc[3]);
            }
        }
    };

    LOADR(0); WRITE(0); LOADR(1);
    __syncthreads();
    for (int rr = 0; rr < 64; ++rr) {
        const int p = rr & 1;
        if (rr + 1 < 64) WRITE(p ^ 1);
        if (rr + 2 < 64) LOADR(rr + 2);
        COMPUTE(p);
        __syncthreads();
    }

    const float br0 = bo_r[co0],     bi0 = bo_i[co0];
    const float br1 = bo_r[co0 + 1], bi1 = bo_i[co0 + 1];
    const int n = px;
    or_out[co0 * NPIX + n]       = acc[0] + br0;
    oi_out[co0 * NPIX + n]       = acc[1] + bi0;
    or_out[(co0 + 1) * NPIX + n] = acc[2] + br1;
    oi_out[(co0 + 1) * NPIX + n] = acc[3] + bi1;
}

// =====================================================================
extern "C" void kernel_launch(void* const* d_in, const int* in_sizes, int n_in,
                              void* d_out, int out_size, void* d_ws, size_t ws_size,
                              hipStream_t stream)
{
    const float* xr   = (const float*)d_in[0];
    const float* xi   = (const float*)d_in[1];
    const float* wq_r = (const float*)d_in[2];
    const float* wq_i = (const float*)d_in[3];
    const float* bq_r = (const float*)d_in[4];
    const float* bq_i = (const float*)d_in[5];
    const float* wk_r = (const float*)d_in[6];
    const float* wk_i = (const float*)d_in[7];
    const float* bk_r = (const float*)d_in[8];
    const float* bk_i = (const float*)d_in[9];
    const float* wv_r = (const float*)d_in[10];
    const float* wv_i = (const float*)d_in[11];
    const float* bv_r = (const float*)d_in[12];
    const float* bv_i = (const float*)d_in[13];
    const float* wo_r = (const float*)d_in[14];
    const float* wo_i = (const float*)d_in[15];
    const float* bo_r = (const float*)d_in[16];
    const float* bo_i = (const float*)d_in[17];

    float* ws  = (float*)d_ws;
    float* qm  = ws;
    float* qp  = qm  + 294912;
    float* km  = qp  + 294912;
    float* kp  = km  + 294912;
    float* vmp = kp  + 294912;        // 589824 floats (interleaved vm,vp)
    float* ar  = vmp + 589824;
    float* ai  = ar  + 294912;

    float* out = (float*)d_out;
    float* o_r = out;
    float* o_i = out + 294912;
    float* qkm = out + 589824;
    float* qkp = qkm + 42467328;

    conv_qkv_kernel<<<dim3(9, 64), 256, 0, stream>>>(
        xr, xi, wq_r, wq_i, bq_r, bq_i, wk_r, wk_i, bk_r, bk_i,
        wv_r, wv_i, bv_r, bv_i, qm, qp, km, kp, vmp);

    attn_kernel<<<dim3(4608), 256, 0, stream>>>(
        qm, qp, km, kp, vmp, qkm, qkp, ar, ai);

    conv_o_kernel<<<dim3(9, 64), 256, 0, stream>>>(
        ar, ai, wo_r, wo_i, bo_r, bo_i, o_r, o_i);
}